// Round 3
// baseline (834.253 us; speedup 1.0000x reference)
//
#include <hip/hip_runtime.h>
#include <math.h>

// Problem constants: B=2, S=2048, D=512, H=8, DH=64, HID=2048, tokens M=4096.
#define S_ 2048
#define D_ 512
#define H_ 8
#define DH_ 64
#define HID_ 2048
#define NT_ 4096          // B*S tokens
#define K3D_ 1536         // 3*D

typedef unsigned short u16;
typedef __bf16 bf16x8 __attribute__((ext_vector_type(8)));
typedef float f32x4 __attribute__((ext_vector_type(4)));

__device__ __forceinline__ float b2f(u16 u) {
  union { unsigned int i; float f; } v; v.i = ((unsigned int)u) << 16; return v.f;
}
__device__ __forceinline__ u16 f2b(float f) {
  union { float f; unsigned int i; } v; v.f = f;
  unsigned int u = v.i;
  u += 0x7fffu + ((u >> 16) & 1u);   // RN-even; inputs finite
  return (u16)(u >> 16);
}

// ---------------------------------------------------------------------------
// fp32 -> bf16 elementwise convert (8 elems/thread)
// ---------------------------------------------------------------------------
__global__ __launch_bounds__(256) void cvt_kernel(
    const float* __restrict__ in, u16* __restrict__ out, int n8) {
  int i = blockIdx.x * 256 + threadIdx.x;
  if (i >= n8) return;
  size_t base = (size_t)i * 8;
  float4 a = *(const float4*)(in + base);
  float4 b = *(const float4*)(in + base + 4);
  u16 ov[8] = {f2b(a.x), f2b(a.y), f2b(a.z), f2b(a.w),
               f2b(b.x), f2b(b.y), f2b(b.z), f2b(b.w)};
  *(uint4*)(out + base) = *(uint4*)ov;
}

// ---------------------------------------------------------------------------
// Transpose+convert: in fp32 [R,C] row-major -> out bf16 [C,R] row-major
// ---------------------------------------------------------------------------
__global__ __launch_bounds__(256) void transpose_kernel(
    const float* __restrict__ in, u16* __restrict__ out, int R, int C) {
  int idx = blockIdx.x * 256 + threadIdx.x;
  if (idx >= R * C) return;
  int r = idx / C, c = idx % C;
  out[(size_t)c * R + r] = f2b(in[idx]);
}

// V chunk of kqv (bf16) -> Vt[bh][dh=64][key=2048] (bf16)
__global__ __launch_bounds__(256) void vt_kernel(
    const u16* __restrict__ kqv, u16* __restrict__ vt) {
  int bh = blockIdx.y, b = bh >> 3, h = bh & 7;
  const u16* V = kqv + (size_t)b * S_ * K3D_ + 2 * D_ + h * DH_;
  u16* O = vt + (size_t)bh * DH_ * S_;
  int idx = blockIdx.x * 256 + threadIdx.x;   // over 2048*64
  int r = idx >> 6, c = idx & 63;             // r = key token, c = dh
  O[(size_t)c * S_ + r] = V[(size_t)r * K3D_ + c];
}

// ---------------------------------------------------------------------------
// MFMA GEMM: C[M,N] = epilogue(A[M,K] @ Bt[N,K]^T); A,Bt bf16.
// Tile 64x64, BK=32, 256 threads = 4 waves; wave w does rows [16w,16w+16).
// mode 0: +bias (fp32), store bf16
// mode 1: +bias, exact GELU, store bf16
// mode 2: *scale + Prev (fp32), store fp32 (attention energy; batch blockIdx.z)
// ---------------------------------------------------------------------------
__global__ __launch_bounds__(256) void gemm_bt(
    const u16* __restrict__ A, const u16* __restrict__ Bt,
    const float* __restrict__ bias, const float* __restrict__ Prev,
    void* __restrict__ Cv,
    int K, int lda, int ldb, int ldc, float scale, int mode) {
  u16* Cb = (u16*)Cv;
  float* Cf = (float*)Cv;
  if (mode == 2) {
    int bz = blockIdx.z;
    int b = bz >> 3, h = bz & 7;
    A    += (size_t)b * S_ * K3D_ + h * DH_ + D_;   // Q (k,q,v order -> q at +D)
    Bt   += (size_t)b * S_ * K3D_ + h * DH_;        // K chunk
    Cf   += (size_t)bz * S_ * S_;
    Prev += (size_t)bz * S_ * S_;
  }
  int tile_m = blockIdx.y * 64, tile_n = blockIdx.x * 64;

  __shared__ alignas(16) u16 As[64 * 40];   // pad 32 -> 40 (16B-aligned rows)
  __shared__ alignas(16) u16 Bs[64 * 40];

  int t = threadIdx.x;
  int w = t >> 6, lane = t & 63, quad = lane >> 4, l16 = lane & 15;
  int srow = t >> 2, schunk = (t & 3) * 8;

  f32x4 acc[4];
#pragma unroll
  for (int i = 0; i < 4; ++i) acc[i] = (f32x4){0.f, 0.f, 0.f, 0.f};

  for (int kb = 0; kb < K; kb += 32) {
    uint4 av = *(const uint4*)(A  + (size_t)(tile_m + srow) * lda + kb + schunk);
    uint4 bv = *(const uint4*)(Bt + (size_t)(tile_n + srow) * ldb + kb + schunk);
    __syncthreads();
    *(uint4*)(&As[srow * 40 + schunk]) = av;
    *(uint4*)(&Bs[srow * 40 + schunk]) = bv;
    __syncthreads();
    bf16x8 a = *(const bf16x8*)(&As[(w * 16 + l16) * 40 + quad * 8]);
#pragma unroll
    for (int nt = 0; nt < 4; ++nt) {
      bf16x8 b = *(const bf16x8*)(&Bs[(nt * 16 + l16) * 40 + quad * 8]);
      acc[nt] = __builtin_amdgcn_mfma_f32_16x16x32_bf16(a, b, acc[nt], 0, 0, 0);
    }
  }

#pragma unroll
  for (int nt = 0; nt < 4; ++nt) {
    int col = tile_n + nt * 16 + l16;
    float bcol = (mode == 2) ? 0.f : bias[col];
#pragma unroll
    for (int r = 0; r < 4; ++r) {
      int row = tile_m + w * 16 + quad * 4 + r;
      float v = acc[nt][r];
      if (mode == 2) {
        Cf[(size_t)row * ldc + col] = v * scale + Prev[(size_t)row * ldc + col];
      } else {
        v += bcol;
        if (mode == 1) v = 0.5f * v * (1.f + erff(v * 0.70710678118654752f));
        Cb[(size_t)row * ldc + col] = f2b(v);
      }
    }
  }
}

// ---------------------------------------------------------------------------
// Fused softmax + P@V. One WG = 16 q-rows of one (b,h), full S keys.
// energy fp32; Vt bf16; ctx bf16.
// ---------------------------------------------------------------------------
__global__ __launch_bounds__(256) void softmax_pv(
    const float* __restrict__ energy, const u16* __restrict__ vt,
    u16* __restrict__ ctx) {
  int bh = blockIdx.y, b = bh >> 3, h = bh & 7;
  const float* E = energy + (size_t)bh * S_ * S_;
  const u16* Vt  = vt + (size_t)bh * DH_ * S_;

  int t = threadIdx.x;
  int qr = t >> 4, l16 = t & 15;
  int qi = blockIdx.x * 16 + qr;
  const float* erow = E + (size_t)qi * S_;

  // --- single-pass online (m,l), float4 per thread step ---
  float m = -1e30f, l = 0.f;
  for (int k0 = l16 * 4; k0 < S_; k0 += 64) {
    float4 e4 = *(const float4*)(erow + k0);
    float mt = fmaxf(fmaxf(e4.x, e4.y), fmaxf(e4.z, e4.w));
    float mn = fmaxf(m, mt);
    l = l * __expf(m - mn) + __expf(e4.x - mn) + __expf(e4.y - mn) +
        __expf(e4.z - mn) + __expf(e4.w - mn);
    m = mn;
  }
#pragma unroll
  for (int off = 8; off; off >>= 1) {
    float m2 = __shfl_xor(m, off, 16);
    float l2 = __shfl_xor(l, off, 16);
    float mn = fmaxf(m, m2);
    l = l * __expf(m - mn) + l2 * __expf(m2 - mn);
    m = mn;
  }

  __shared__ float linv[16];
  __shared__ alignas(16) u16 Pt[16 * 72];   // pad 64 -> 72
  if (l16 == 0) linv[qr] = 1.f / l;

  int w = t >> 6, lane = t & 63, quad = lane >> 4, wl16 = lane & 15;
  f32x4 acc = (f32x4){0.f, 0.f, 0.f, 0.f};

  for (int kb = 0; kb < S_; kb += 64) {
    __syncthreads();                         // protect Pt from prior reads
#pragma unroll
    for (int jj = 0; jj < 4; ++jj) {
      int k = jj * 16 + l16;
      Pt[qr * 72 + k] = f2b(__expf(erow[kb + k] - m));
    }
    __syncthreads();
#pragma unroll
    for (int ks = 0; ks < 2; ++ks) {
      bf16x8 a = *(const bf16x8*)(&Pt[wl16 * 72 + ks * 32 + quad * 8]);
      bf16x8 bb = *(const bf16x8*)(Vt + (size_t)(w * 16 + wl16) * S_ + kb + ks * 32 + quad * 8);
      acc = __builtin_amdgcn_mfma_f32_16x16x32_bf16(a, bb, acc, 0, 0, 0);
    }
  }

#pragma unroll
  for (int r = 0; r < 4; ++r) {
    int q = quad * 4 + r;                    // C/D row
    float v = acc[r] * linv[q];
    size_t row = (size_t)b * S_ + blockIdx.x * 16 + q;
    ctx[row * D_ + h * DH_ + w * 16 + wl16] = f2b(v);
  }
}

// ---------------------------------------------------------------------------
// LayerNorm: o = LN(a + r) * g + be. a bf16; r fp32 or bf16; o fp32 or bf16.
// One wave per 512-elem row, 4 rows/WG.
// ---------------------------------------------------------------------------
__global__ __launch_bounds__(256) void ln_kernel(
    const u16* __restrict__ a, const void* __restrict__ rsrc,
    const float* __restrict__ g, const float* __restrict__ be,
    void* __restrict__ o, int r_f32, int o_f32) {
  int row = blockIdx.x * 4 + (threadIdx.x >> 6);
  int lane = threadIdx.x & 63;
  size_t base = (size_t)row * D_ + lane * 8;
  uint4 av = *(const uint4*)(a + base);
  const u16* ap = (const u16*)&av;
  float rv[8];
  if (r_f32) {
    float4 r0 = *(const float4*)((const float*)rsrc + base);
    float4 r1 = *(const float4*)((const float*)rsrc + base + 4);
    rv[0] = r0.x; rv[1] = r0.y; rv[2] = r0.z; rv[3] = r0.w;
    rv[4] = r1.x; rv[5] = r1.y; rv[6] = r1.z; rv[7] = r1.w;
  } else {
    uint4 rr = *(const uint4*)((const u16*)rsrc + base);
    const u16* rp = (const u16*)&rr;
#pragma unroll
    for (int j = 0; j < 8; ++j) rv[j] = b2f(rp[j]);
  }
  float tv[8], s = 0.f, sq = 0.f;
#pragma unroll
  for (int j = 0; j < 8; ++j) {
    float xx = b2f(ap[j]) + rv[j];
    tv[j] = xx; s += xx; sq += xx * xx;
  }
#pragma unroll
  for (int off = 32; off; off >>= 1) {
    s  += __shfl_xor(s, off);
    sq += __shfl_xor(sq, off);
  }
  float mu  = s * (1.f / 512.f);
  float var = fmaxf(sq * (1.f / 512.f) - mu * mu, 0.f);
  float wv  = rsqrtf(var + 1e-5f);
  float4 g0 = *(const float4*)(g + lane * 8);
  float4 g1 = *(const float4*)(g + lane * 8 + 4);
  float4 b0 = *(const float4*)(be + lane * 8);
  float4 b1 = *(const float4*)(be + lane * 8 + 4);
  float gv[8] = {g0.x, g0.y, g0.z, g0.w, g1.x, g1.y, g1.z, g1.w};
  float bv[8] = {b0.x, b0.y, b0.z, b0.w, b1.x, b1.y, b1.z, b1.w};
  if (o_f32) {
    float ov[8];
#pragma unroll
    for (int j = 0; j < 8; ++j) ov[j] = (tv[j] - mu) * wv * gv[j] + bv[j];
    *(float4*)((float*)o + base)     = *(float4*)(ov);
    *(float4*)((float*)o + base + 4) = *(float4*)(ov + 4);
  } else {
    u16 ov[8];
#pragma unroll
    for (int j = 0; j < 8; ++j) ov[j] = f2b((tv[j] - mu) * wv * gv[j] + bv[j]);
    *(uint4*)((u16*)o + base) = *(uint4*)ov;
  }
}

// ---------------------------------------------------------------------------
// Workspace plan (29.5 MiB, lifetime-aliased; u16 element offsets):
//   R0 [8,388,608]: kqv (steps 2-4) ; vt in tail [6,291,456..) (4-5) ;
//                   attn in head [0..2,097,152) (6-7) ; ff whole (8-9)
//   R2 [2,097,152]: ctx (5-6) then f2 (9-10)
//   R3 [2,097,152]: hbuf (7-10)
//   R4 [2,097,152]: xb (1-2) then fc1_wt [0..1,048,576) + fc2_wt [1,048,576..)
//   WA [786,432]:   kqv_wt (->2) then out_wt (->6)
// ---------------------------------------------------------------------------
extern "C" void kernel_launch(void* const* d_in, const int* in_sizes, int n_in,
                              void* d_out, int out_size, void* d_ws, size_t ws_size,
                              hipStream_t stream) {
  const float* x     = (const float*)d_in[0];
  const float* prev  = (const float*)d_in[1];
  const float* kqv_w = (const float*)d_in[2];
  const float* kqv_b = (const float*)d_in[3];
  const float* out_w = (const float*)d_in[4];
  const float* out_b = (const float*)d_in[5];
  const float* fc1_w = (const float*)d_in[6];
  const float* fc1_b = (const float*)d_in[7];
  const float* fc2_w = (const float*)d_in[8];
  const float* fc2_b = (const float*)d_in[9];
  const float* ln1_g = (const float*)d_in[10];
  const float* ln1_b = (const float*)d_in[11];
  const float* ln2_g = (const float*)d_in[12];
  const float* ln2_b = (const float*)d_in[13];

  float* outp   = (float*)d_out;                    // [4096,512] fp32
  float* energy = outp + (size_t)NT_ * D_;          // [16,2048,2048] fp32

  u16* ws = (u16*)d_ws;
  u16* R0 = ws;                       // 8,388,608
  u16* R2 = R0 + (size_t)8388608;     // 2,097,152
  u16* R3 = R2 + (size_t)2097152;     // 2,097,152
  u16* R4 = R3 + (size_t)2097152;     // 2,097,152
  u16* WA = R4 + (size_t)2097152;     // 786,432   (total 15,466,496 u16 = 29.5 MiB)

  u16* kqv    = R0;
  u16* vt     = R0 + (size_t)6291456;
  u16* attn   = R0;
  u16* ff     = R0;
  u16* ctx    = R2;  u16* f2     = R2;
  u16* hbuf   = R3;
  u16* xb     = R4;
  u16* fc1_wt = R4;  u16* fc2_wt = R4 + (size_t)1048576;
  u16* kqv_wt = WA;  u16* out_wt = WA;

  // step 1: xb = bf16(x); kqv_wt
  cvt_kernel<<<(NT_ * D_ / 8 + 255) / 256, 256, 0, stream>>>(x, xb, NT_ * D_ / 8);
  transpose_kernel<<<(D_ * K3D_ + 255) / 256, 256, 0, stream>>>(kqv_w, kqv_wt, D_, K3D_);

  // step 2: kqv = xb @ kqv_w + b : M=4096 N=1536 K=512
  gemm_bt<<<dim3(K3D_ / 64, NT_ / 64, 1), 256, 0, stream>>>(
      xb, kqv_wt, kqv_b, nullptr, kqv, D_, D_, D_, K3D_, 1.f, 0);

  // step 1b: remaining weight transposes (xb, kqv_wt now dead)
  transpose_kernel<<<(D_ * HID_ + 255) / 256, 256, 0, stream>>>(fc1_w, fc1_wt, D_, HID_);
  transpose_kernel<<<(HID_ * D_ + 255) / 256, 256, 0, stream>>>(fc2_w, fc2_wt, HID_, D_);
  transpose_kernel<<<(D_ * D_ + 255) / 256, 256, 0, stream>>>(out_w, out_wt, D_, D_);

  // step 3: energy = 0.125 * q k^T + prev  (fp32 out): per (b,h), M=N=2048 K=64
  gemm_bt<<<dim3(S_ / 64, S_ / 64, 16), 256, 0, stream>>>(
      kqv, kqv, nullptr, prev, energy, DH_, K3D_, K3D_, S_, 0.125f, 2);

  // step 4: Vt for PV MFMA
  vt_kernel<<<dim3((S_ * DH_) / 256, 16), 256, 0, stream>>>(kqv, vt);

  // step 5: softmax + P@V -> ctx   (kqv dead after this)
  softmax_pv<<<dim3(S_ / 16, 16), 256, 0, stream>>>(energy, vt, ctx);

  // step 6: attn = ctx @ out_w + b  (bf16, into R0 head)
  gemm_bt<<<dim3(D_ / 64, NT_ / 64, 1), 256, 0, stream>>>(
      ctx, out_wt, out_b, nullptr, attn, D_, D_, D_, D_, 1.f, 0);

  // step 7: h = LN1(attn + x)  -> hbuf bf16   (r fp32, o bf16)
  ln_kernel<<<NT_ / 4, 256, 0, stream>>>(attn, x, ln1_g, ln1_b, hbuf, 1, 0);

  // step 8: ff = gelu(h @ fc1_w + b)  (writes all R0; attn/vt dead)
  gemm_bt<<<dim3(HID_ / 64, NT_ / 64, 1), 256, 0, stream>>>(
      hbuf, fc1_wt, fc1_b, nullptr, ff, D_, D_, D_, HID_, 1.f, 1);

  // step 9: f2 = ff @ fc2_w + b  (writes R2; ctx dead)
  gemm_bt<<<dim3(D_ / 64, NT_ / 64, 1), 256, 0, stream>>>(
      ff, fc2_wt, fc2_b, nullptr, f2, HID_, HID_, HID_, D_, 1.f, 0);

  // step 10: out = LN2(f2 + h) -> fp32  (r bf16, o fp32)
  ln_kernel<<<NT_ / 4, 256, 0, stream>>>(f2, hbuf, ln2_g, ln2_b, outp, 0, 1);
}